// Round 18
// baseline (288.254 us; speedup 1.0000x reference)
//
#include <hip/hip_runtime.h>

typedef unsigned short u16;
typedef unsigned int   u32;
typedef __bf16 bf16x8 __attribute__((ext_vector_type(8)));
typedef float  f32x4  __attribute__((ext_vector_type(4)));

__device__ __forceinline__ u16 f2bf(float f) {
    u32 u = __builtin_bit_cast(u32, f);
    u32 r = (u + 0x7FFFu + ((u >> 16) & 1u)) >> 16;
    return (u16)r;
}
__device__ __forceinline__ u32 pk2bf(float lo, float hi) {
    return (u32)f2bf(lo) | ((u32)f2bf(hi) << 16);
}
__device__ __forceinline__ float bf2f(u16 v) {
    return __builtin_bit_cast(float, (u32)v << 16);
}
__device__ __forceinline__ float fexp2(float x) { return __builtin_amdgcn_exp2f(x); }
__device__ __forceinline__ float flog2(float x) { return __builtin_amdgcn_logf(x); }
__device__ __forceinline__ f32x4 mfma16(bf16x8 a, bf16x8 b, f32x4 c) {
    return __builtin_amdgcn_mfma_f32_16x16x32_bf16(a, b, c, 0, 0, 0);
}
__device__ __forceinline__ bf16x8 ld8(const u16* p) {
    return __builtin_bit_cast(bf16x8, *(const uint4*)p);
}
__device__ __forceinline__ void gload_lds16(const u16* g, u16* l) {
    __builtin_amdgcn_global_load_lds(
        (__attribute__((address_space(1))) void*)g,
        (__attribute__((address_space(3))) void*)l, 16, 0, 0);
}

// ---------------- fused prep: kvin + new_mem copy + pos cvt + transposes + convw ----------------
__global__ void prep_all(const float* __restrict__ x, const float* __restrict__ mem,
                         const float* __restrict__ cmem, const float* __restrict__ pos,
                         const float* __restrict__ Wq, const float* __restrict__ Wkv,
                         const float* __restrict__ Wout, const float* __restrict__ convw,
                         u16* __restrict__ kvin, u16* __restrict__ peb,
                         u16* __restrict__ WqT, u16* __restrict__ WkvT,
                         u16* __restrict__ WoutT, u16* __restrict__ convWT,
                         float* __restrict__ newmem) {
    __shared__ float tile[32][33];
    const int bid = blockIdx.x, tid = threadIdx.x;
    if (bid < 9216) {
        const size_t i = ((size_t)bid * 256 + tid) * 4;
        const int row = (int)(i >> 10), col = (int)(i & 1023);
        const int b = row / 2304, j = row - b * 2304;
        const float* src;
        size_t xoff = 0;
        if (j < 256)       src = cmem + ((size_t)(b * 256  + j) << 10);
        else if (j < 1280) src = mem  + ((size_t)(b * 1024 + j - 256) << 10);
        else               { xoff = ((size_t)(b * 1024 + j - 1280) << 10); src = x + xoff; }
        float4 v = *(const float4*)(src + col);
        uint2 o;
        o.x = (u32)f2bf(v.x) | ((u32)f2bf(v.y) << 16);
        o.y = (u32)f2bf(v.z) | ((u32)f2bf(v.w) << 16);
        *(uint2*)(kvin + i) = o;
        if (j >= 1280) *(float4*)(newmem + xoff + col) = v;   // new_mem = x, fused
    } else if (bid < 11520) {
        const int i = ((bid - 9216) * 256 + tid) * 4;
        float4 v = *(const float4*)(pos + i);
        uint2 o;
        o.x = (u32)f2bf(v.x) | ((u32)f2bf(v.y) << 16);
        o.y = (u32)f2bf(v.z) | ((u32)f2bf(v.w) << 16);
        *(uint2*)(peb + i) = o;
    } else if (bid < 15616) {
        const float* in; u16* out; int K, N, bx, by;
        if (bid < 12544)      { in = Wq;   out = WqT;   K = 1024; N = 1024;
                                const int t = bid - 11520; bx = t & 31, by = t >> 5; }
        else if (bid < 14592) { in = Wkv;  out = WkvT;  K = 1024; N = 2048;
                                const int t = bid - 12544; bx = t & 63, by = t >> 6; }
        else                  { in = Wout; out = WoutT; K = 1024; N = 1024;
                                const int t = bid - 14592; bx = t & 31, by = t >> 5; }
        const int tx = tid & 31, ty = tid >> 5;
        #pragma unroll
        for (int i = 0; i < 32; i += 8)
            tile[ty + i][tx] = in[(size_t)(by * 32 + ty + i) * N + bx * 32 + tx];
        __syncthreads();
        #pragma unroll
        for (int i = 0; i < 32; i += 8)
            out[(size_t)(bx * 32 + ty + i) * K + by * 32 + tx] = f2bf(tile[tx][ty + i]);
    } else {
        const int o = bid - 15616;
        const float* src = convw + (size_t)o * 4096;
        u16* dst = convWT + (size_t)o * 4096;
        #pragma unroll
        for (int it = 0; it < 4; ++it) {
            const int d = it * 256 + tid;
            float4 v = *(const float4*)(src + d * 4);
            dst[d]        = f2bf(v.x);
            dst[1024 + d] = f2bf(v.y);
            dst[2048 + d] = f2bf(v.z);
            dst[3072 + d] = f2bf(v.w);
        }
    }
}

// ---------------- merged conv/KV/Q GEMM (long conv blocks first, per-XCD M-chunks) ----------------
__global__ __launch_bounds__(256)
void gemm_fused(const u16* __restrict__ kvin, const u16* __restrict__ WqT,
                const u16* __restrict__ WkvT, const u16* __restrict__ convWT,
                u16* __restrict__ Qb, u16* __restrict__ KVb, u16* __restrict__ Vtb,
                float* __restrict__ convOut, const float* __restrict__ convb) {
    __shared__ __align__(16) u16 sh[64 * 136];
    u16* As = sh;
    u16* Bs = sh + 128 * 32;
    const int bid = blockIdx.x, tid = threadIdx.x;
    int seg, local;
    if (bid < 64)        { seg = 2; local = bid; }
    else if (bid < 1216) { seg = 1; local = bid - 64; }
    else                 { seg = 0; local = bid - 1216; }
    const int xcd = local & 7, idx = local >> 3;
    int m0, n0;
    const u16* BT; int N, K, rowblk, rowstride, rowoff;
    if (seg == 0) {
        m0 = (xcd * 4 + (idx & 3)) * 128; n0 = (idx >> 2) * 128;
        BT = WqT;    N = 1024; K = 1024; rowblk = 1024; rowstride = 2304; rowoff = 1280;
    } else if (seg == 1) {
        m0 = (xcd * 9 + idx % 9) * 128;   n0 = (idx / 9) * 128;
        BT = WkvT;   N = 2048; K = 1024; rowblk = 9216; rowstride = 0;    rowoff = 0;
    } else {
        m0 = ((xcd & 3) * 2 + (idx & 1)) * 128; n0 = ((xcd >> 2) * 4 + (idx >> 1)) * 128;
        BT = convWT; N = 1024; K = 4096; rowblk = 256;  rowstride = 576;  rowoff = 64;
    }

    const int wv = tid >> 6, lane = tid & 63;
    const int fr = lane & 15, fg = lane >> 4;
    const int wr = (wv >> 1) * 64, wc = (wv & 1) * 64;

    size_t aoff[2], boff[2];
    #pragma unroll
    for (int i = 0; i < 2; ++i) {
        const int ag = m0 + wv * 32 + i * 16 + (lane >> 2);
        const size_t arow = (size_t)(ag / rowblk) * rowstride + (ag % rowblk) + rowoff;
        aoff[i] = arow * K + (lane & 3) * 8;
        const int bg = n0 + wv * 32 + i * 16 + (lane >> 2);
        boff[i] = (size_t)bg * K + (lane & 3) * 8;
    }

    f32x4 acc[4][4] = {};
    const int nk = K / 32;
    for (int kt = 0; kt < nk; ++kt) {
        __syncthreads();
        #pragma unroll
        for (int i = 0; i < 2; ++i) {
            gload_lds16(kvin + aoff[i] + kt * 32, As + wv * 1024 + i * 512);
            gload_lds16(BT + boff[i] + kt * 32, Bs + wv * 1024 + i * 512);
        }
        __syncthreads();
        bf16x8 af[4], bfv[4];
        #pragma unroll
        for (int i = 0; i < 4; ++i)
            af[i] = ld8(As + (wr + i * 16 + fr) * 32 + fg * 8);
        #pragma unroll
        for (int i = 0; i < 4; ++i)
            bfv[i] = ld8(Bs + (wc + i * 16 + fr) * 32 + fg * 8);
        #pragma unroll
        for (int mi = 0; mi < 4; ++mi)
            #pragma unroll
            for (int ni = 0; ni < 4; ++ni)
                acc[mi][ni] = mfma16(af[mi], bfv[ni], acc[mi][ni]);
    }
    if (seg == 1 && n0 >= 1024) {
        const int bb = m0 / 2304;
        const int j0 = m0 - bb * 2304;
        const int c0 = n0 - 1024;
        #pragma unroll
        for (int p = 0; p < 2; ++p) {
            __syncthreads();
            if ((wv & 1) == p) {
                #pragma unroll
                for (int mi = 0; mi < 4; ++mi)
                    #pragma unroll
                    for (int ni = 0; ni < 4; ++ni)
                        #pragma unroll
                        for (int r = 0; r < 4; ++r)
                            sh[(ni * 16 + fr) * 136 + wr + mi * 16 + fg * 4 + r]
                                = f2bf(acc[mi][ni][r]);
            }
            __syncthreads();
            #pragma unroll
            for (int it = 0; it < 2; ++it) {
                const int idx2 = it * 256 + tid;
                const int d = idx2 >> 3, jo = (idx2 & 7) * 16;
                *(uint4*)(Vtb + ((size_t)(bb * 1024 + c0 + p * 64 + d)) * 2304 + j0 + jo)
                    = *(const uint4*)(sh + d * 136 + jo);
            }
        }
        return;
    }
    #pragma unroll
    for (int mi = 0; mi < 4; ++mi) {
        #pragma unroll
        for (int ni = 0; ni < 4; ++ni) {
            const int col = n0 + wc + ni * 16 + fr;
            const float bv = (seg == 2) ? convb[col] : 0.0f;
            #pragma unroll
            for (int r = 0; r < 4; ++r) {
                const int row = m0 + wr + mi * 16 + fg * 4 + r;
                const float v = acc[mi][ni][r] + bv;
                if (seg == 2)      convOut[(size_t)row * 1024 + col] = v;
                else if (seg == 0) Qb[(size_t)row * 1024 + col] = f2bf(v);
                else               KVb[(size_t)row * 2048 + col] = f2bf(v);
            }
        }
    }
}

// ---------------- Wout GEMM (XCD m-chunk swizzled, 1D grid 256) ----------------
__global__ __launch_bounds__(256)
void gemm_bt(const u16* __restrict__ A, const u16* __restrict__ BT,
             float* __restrict__ Cf, const float* __restrict__ bias, int K) {
    __shared__ __align__(16) u16 sh[8192];
    u16* As = sh;
    u16* Bs = sh + 128 * 32;
    const int tid = threadIdx.x;
    const int xcd = blockIdx.x & 7, idx = blockIdx.x >> 3;
    const int m0 = (xcd * 4 + (idx & 3)) * 128, n0 = (idx >> 2) * 128;
    const int wv = tid >> 6, lane = tid & 63;
    const int fr = lane & 15, fg = lane >> 4;
    const int wr = (wv >> 1) * 64, wc = (wv & 1) * 64;
    size_t aoff[2], boff[2];
    #pragma unroll
    for (int i = 0; i < 2; ++i) {
        const int ag = m0 + wv * 32 + i * 16 + (lane >> 2);
        aoff[i] = (size_t)ag * K + (lane & 3) * 8;
        const int bg = n0 + wv * 32 + i * 16 + (lane >> 2);
        boff[i] = (size_t)bg * K + (lane & 3) * 8;
    }
    f32x4 acc[4][4] = {};
    const int nk = K / 32;
    for (int kt = 0; kt < nk; ++kt) {
        __syncthreads();
        #pragma unroll
        for (int i = 0; i < 2; ++i) {
            gload_lds16(A + aoff[i] + kt * 32, As + wv * 1024 + i * 512);
            gload_lds16(BT + boff[i] + kt * 32, Bs + wv * 1024 + i * 512);
        }
        __syncthreads();
        bf16x8 af[4], bfv[4];
        #pragma unroll
        for (int i = 0; i < 4; ++i)
            af[i] = ld8(As + (wr + i * 16 + fr) * 32 + fg * 8);
        #pragma unroll
        for (int i = 0; i < 4; ++i)
            bfv[i] = ld8(Bs + (wc + i * 16 + fr) * 32 + fg * 8);
        #pragma unroll
        for (int mi = 0; mi < 4; ++mi)
            #pragma unroll
            for (int ni = 0; ni < 4; ++ni)
                acc[mi][ni] = mfma16(af[mi], bfv[ni], acc[mi][ni]);
    }
    #pragma unroll
    for (int mi = 0; mi < 4; ++mi) {
        #pragma unroll
        for (int ni = 0; ni < 4; ++ni) {
            const int col = n0 + wc + ni * 16 + fr;
            const float bv = bias[col];
            #pragma unroll
            for (int r = 0; r < 4; ++r) {
                const int row = m0 + wr + mi * 16 + fg * 4 + r;
                Cf[(size_t)row * 1024 + col] = acc[mi][ni][r] + bv;
            }
        }
    }
}

// ---------------- fused attention (R13-proven): swapped softmax, b64 sc, 3-barrier pipeline ----------------
__global__ __launch_bounds__(256, 2)
void attn_fused10(const u16* __restrict__ Qb, const u16* __restrict__ KVb,
                  const u16* __restrict__ Vtb, const u16* __restrict__ peb,
                  u16* __restrict__ O01, float* __restrict__ lsep,
                  u16* __restrict__ O2) {
    const int bid = blockIdx.x;
    const int xcd = bid & 7, ii = bid >> 3;
    const int G = xcd * 12 + (ii >> 4), qt = ii & 15;
    const int b = G / 24, rem = G - b * 24;
    const int h = rem / 3, sp = rem - (rem / 3) * 3;

    const int tid = threadIdx.x, w = tid >> 6, lane = tid & 63;
    const int fr = lane & 15, fg = lane >> 4;
    const int q0 = qt * 64, q0w = q0 + w * 16;
    const int n64 = min(2304, q0 + 1344) >> 6;
    const int base = n64 / 3, rm = n64 - base * 3;
    const int cbeg = sp * base + min(sp, rm);
    const int cnt = base + (sp < rm ? 1 : 0);
    const int kbeg = cbeg << 6, kend = (cbeg + cnt) << 6;

    __shared__ __align__(16) u16 Ks[64 * 128];
    __shared__ __align__(16) u16 Vs[128 * 64];
    __shared__ __align__(16) u16 PEs[2][64 * 128];
    __shared__ __align__(16) u16 sc[4][16][108];

    const u16* kvbase = KVb + (size_t)b * 2304 * 2048 + h * 128;
    const u16* vtbase = Vtb + (size_t)(b * 8 + h) * 128 * 2304;
    const u16* pebase = peb + (size_t)h * 2304 * 128;
    const float scale2 = 0.088388347648318447f * 1.4426950408889634f;

    bf16x8 qf[4];
    {
        const u16* qp = Qb + (size_t)(b * 1024 + q0w + fr) * 1024 + h * 128 + fg * 8;
        #pragma unroll
        for (int dc = 0; dc < 4; ++dc) qf[dc] = ld8(qp + dc * 32);
    }

    const u16* srcK[4];
    const u16* srcV[4];
    const u16* srcP[4];
    #pragma unroll
    for (int i = 0; i < 4; ++i) {
        const int kr = w * 16 + i * 4 + (lane >> 4);
        srcK[i] = kvbase + (size_t)kr * 2048 + (((lane & 15) ^ (kr & 7)) * 8);
        srcP[i] = pebase + (size_t)kr * 128  + (((lane & 15) ^ (kr & 7)) * 8);
        const int vr = w * 32 + i * 8 + (lane >> 3);
        srcV[i] = vtbase + (size_t)vr * 2304 + (((lane & 7) ^ (vr & 7)) * 8);
    }

    // prologue: stage K, V, PE-lo, PE-hi for chunk kbeg
    {
        const int cc0 = (kbeg - q0) >> 6;
        u16* lo = &PEs[(cc0 + 15) & 1][0];
        u16* up = &PEs[(cc0 + 16) & 1][0];
        const size_t jlo = (size_t)(kbeg - q0 + 960) * 128;
        const size_t jup = (size_t)(kbeg - q0 + 1024) * 128;
        #pragma unroll
        for (int i = 0; i < 4; ++i)
            gload_lds16(srcK[i] + (size_t)kbeg * 2048, Ks + w * 2048 + i * 512);
        #pragma unroll
        for (int i = 0; i < 4; ++i)
            gload_lds16(srcV[i] + kbeg, &Vs[0] + w * 2048 + i * 512);
        #pragma unroll
        for (int i = 0; i < 4; ++i)
            gload_lds16(srcP[i] + jlo, lo + w * 2048 + i * 512);
        #pragma unroll
        for (int i = 0; i < 4; ++i)
            gload_lds16(srcP[i] + jup, up + w * 2048 + i * 512);
    }

    f32x4 o[8] = {};
    float mrow = -1e30f, lrow = 0.0f;   // per-lane, q = q0w + fr

    for (int k0 = kbeg; k0 < kend; k0 += 64) {
        const int cc = (k0 - q0) >> 6;
        const bool more = (k0 + 64 < kend);
        __syncthreads();   // B1: drain staged loads

        // ---- S^T = K Q^T + PE^T band, LDS-fed, swapped args ----
        __builtin_amdgcn_s_setprio(1);
        f32x4 s[4] = {};
        #pragma unroll
        for (int kb = 0; kb < 4; ++kb) {
            const int row = kb * 16 + fr;
            #pragma unroll
            for (int dc = 0; dc < 4; ++dc) {
                bf16x8 kf = ld8(Ks + row * 128 + ((dc * 32 + fg * 8) ^ ((row & 7) << 3)));
                s[kb] = mfma16(kf, qf[dc], s[kb]);
            }
        }
        const u16* pl = &PEs[(cc + 15) & 1][0];
        const u16* pu = &PEs[(cc + 16) & 1][0];
        f32x4 pp[5] = {};
        #pragma unroll
        for (int jb = 0; jb < 5; ++jb) {
            const int lstart = 48 - 16 * w + 16 * jb;
            const u16* pbase = (lstart < 64) ? (pl + lstart * 128) : (pu + (lstart - 64) * 128);
            #pragma unroll
            for (int dc = 0; dc < 4; ++dc) {
                bf16x8 pf = ld8(pbase + fr * 128 + ((dc * 32 + fg * 8) ^ ((fr & 7) << 3)));
                pp[jb] = mfma16(pf, qf[dc], pp[jb]);
            }
        }
        __builtin_amdgcn_s_setprio(0);
        #pragma unroll
        for (int jb = 0; jb < 5; ++jb) {
            uint2 pk;
            pk.x = pk2bf(pp[jb][0], pp[jb][1]);
            pk.y = pk2bf(pp[jb][2], pp[jb][3]);
            *(uint2*)(&sc[w][fr][jb * 16 + fg * 4]) = pk;
        }
        asm volatile("s_waitcnt lgkmcnt(0)" ::: "memory");

        __syncthreads();   // B2: Ks/PEs reads complete -> safe to restage

        if (more) {
            #pragma unroll
            for (int i = 0; i < 4; ++i)
                gload_lds16(srcK[i] + (size_t)(k0 + 64) * 2048, Ks + w * 2048 + i * 512);
            u16* pslot = &PEs[(cc + 15) & 1][0];
            const size_t jnext = (size_t)(k0 - q0 + 1088) * 128;
            #pragma unroll
            for (int i = 0; i < 4; ++i)
                gload_lds16(srcP[i] + jnext, pslot + w * 2048 + i * 512);
        }

        // ---- combine + mask + online softmax: q = fr, k = k0 + kb*16 + fg*4 + r ----
        const bool need_mask = (k0 + 63) > (q0w + 1280);
        float pv[4][4];
        float mx = mrow;
        #pragma unroll
        for (int kb = 0; kb < 4; ++kb) {
            #pragma unroll
            for (int r = 0; r < 4; ++r) {
                float v = (s[kb][r] + bf2f(sc[w][fr][kb * 16 + fg * 4 + r + 15 - fr])) * scale2;
                if (need_mask && (k0 + kb * 16 + fg * 4 + r) > (q0w + fr + 1280)) v = -1e30f;
                pv[kb][r] = v;
                mx = fmaxf(mx, v);
            }
        }
        mx = fmaxf(mx, __shfl_xor(mx, 16));
        mx = fmaxf(mx, __shfl_xor(mx, 32));
        if (!__all(mx - mrow <= 8.0f)) {
            const float alpha = fexp2(mrow - mx);
            mrow = mx;
            lrow *= alpha;
            float a4[4];
            #pragma unroll
            for (int r = 0; r < 4; ++r) a4[r] = __shfl(alpha, fg * 4 + r);
            #pragma unroll
            for (int db = 0; db < 8; ++db)
                #pragma unroll
                for (int r = 0; r < 4; ++r) o[db][r] *= a4[r];
        }
        float rsum = 0.0f;
        #pragma unroll
        for (int kb = 0; kb < 4; ++kb)
            #pragma unroll
            for (int r = 0; r < 4; ++r) {
                const float p = fexp2(pv[kb][r] - mrow);
                pv[kb][r] = p;
                rsum += p;
            }
        rsum += __shfl_xor(rsum, 16);
        rsum += __shfl_xor(rsum, 32);
        lrow += rsum;
        #pragma unroll
        for (int kb = 0; kb < 4; ++kb) {
            uint2 pk;
            pk.x = pk2bf(pv[kb][0], pv[kb][1]);
            pk.y = pk2bf(pv[kb][2], pv[kb][3]);
            *(uint2*)(&sc[w][fr][kb * 16 + fg * 4]) = pk;
        }
        asm volatile("s_waitcnt lgkmcnt(0)" ::: "memory");
        // ---- O += P V ----
        __builtin_amdgcn_s_setprio(1);
        #pragma unroll
        for (int ks = 0; ks < 2; ++ks) {
            bf16x8 pa = __builtin_bit_cast(bf16x8, *(const uint4*)(&sc[w][fr][ks * 32 + fg * 8]));
            #pragma unroll
            for (int db = 0; db < 8; ++db) {
                const int d = db * 16 + fr;
                bf16x8 vf = ld8(Vs + d * 64 + ((ks * 32 + fg * 8) ^ ((d & 7) << 3)));
                o[db] = mfma16(pa, vf, o[db]);
            }
        }
        __builtin_amdgcn_s_setprio(0);

        __syncthreads();   // B3: Vs reads complete

        if (more) {
            #pragma unroll
            for (int i = 0; i < 4; ++i)
                gload_lds16(srcV[i] + (k0 + 64), &Vs[0] + w * 2048 + i * 512);
        }
    }
    // ---- epilogue: normalized partial + lse (log2 domain) ----
    const float inv = 1.0f / lrow;
    float inv4[4];
    #pragma unroll
    for (int r = 0; r < 4; ++r) inv4[r] = __shfl(inv, fg * 4 + r);
    u16* dst = (sp == 2) ? O2 : (O01 + (size_t)sp * 4194304);
    #pragma unroll
    for (int db = 0; db < 8; ++db)
        #pragma unroll
        for (int r = 0; r < 4; ++r)
            dst[(size_t)(b * 1024 + q0w + fg * 4 + r) * 1024 + h * 128 + db * 16 + fr]
                = f2bf(o[db][r] * inv4[r]);
    if (lane < 16)
        lsep[sp * 32768 + (b * 8 + h) * 1024 + q0w + lane] = mrow + flog2(lrow);
}

// combine 3 flash partials (lse in log2 domain)
__global__ void attn_combine(const u16* __restrict__ O01, const float* __restrict__ lsep,
                             u16* __restrict__ O2) {
    const int i = (blockIdx.x * 256 + threadIdx.x) * 8;
    const int row = i >> 10;
    const int b = row >> 10, q = row & 1023;
    const int h = (i & 1023) >> 7;
    const int li = (b * 8 + h) * 1024 + q;
    const float l0 = lsep[li], l1 = lsep[li + 32768], l2 = lsep[li + 65536];
    const float M = fmaxf(l0, fmaxf(l1, l2));
    const float w0 = fexp2(l0 - M), w1 = fexp2(l1 - M), w2 = fexp2(l2 - M);
    const float inv = 1.0f / (w0 + w1 + w2);
    uint4 a = *(const uint4*)(O01 + i);
    uint4 c = *(const uint4*)(O01 + 4194304 + i);
    uint4 e = *(const uint4*)(O2 + i);
    const u16* ap = (const u16*)&a;
    const u16* cp = (const u16*)&c;
    const u16* ep = (const u16*)&e;
    u16 ov[8];
    #pragma unroll
    for (int j = 0; j < 8; ++j)
        ov[j] = f2bf((w0 * bf2f(ap[j]) + w1 * bf2f(cp[j]) + w2 * bf2f(ep[j])) * inv);
    *(uint4*)(O2 + i) = *(const uint4*)ov;
}

// ---------------- launch ----------------

extern "C" void kernel_launch(void* const* d_in, const int* in_sizes, int n_in,
                              void* d_out, int out_size, void* d_ws, size_t ws_size,
                              hipStream_t stream) {
    const float* x     = (const float*)d_in[0];
    const float* mem   = (const float*)d_in[1];
    const float* cmem  = (const float*)d_in[2];
    const float* pos   = (const float*)d_in[3];
    const float* Wq    = (const float*)d_in[5];
    const float* Wkv   = (const float*)d_in[6];
    const float* Wout  = (const float*)d_in[7];
    const float* bout  = (const float*)d_in[8];
    const float* convw = (const float*)d_in[9];
    const float* convb = (const float*)d_in[10];
    float* out = (float*)d_out;

    u16* ws = (u16*)d_ws;
    size_t off = 0;
    u16* kvin   = ws + off; off += (size_t)9216 * 1024;   // also reused as O-partials
    u16* WqT    = ws + off; off += (size_t)1024 * 1024;
    u16* WkvT   = ws + off; off += (size_t)2048 * 1024;
    u16* WoutT  = ws + off; off += (size_t)1024 * 1024;
    u16* convWT = ws + off; off += (size_t)1024 * 4096;
    u16* peb    = ws + off; off += (size_t)8 * 2304 * 128;
    u16* Qb     = ws + off; off += (size_t)4096 * 1024;
    u16* KVb    = ws + off; off += (size_t)9216 * 2048;
    u16* Vtb    = ws + off; off += (size_t)4 * 8 * 128 * 2304;
    u16* attn   = ws + off; off += (size_t)4096 * 1024;

    u16* O01 = kvin;                             // splits 0,1: 2 x 4194304 u16
    float* lsep = (float*)(kvin + 8388608);      // 3 x 32768 f32

    prep_all<<<16640, 256, 0, stream>>>(x, mem, cmem, pos, Wq, Wkv, Wout, convw,
                                        kvin, peb, WqT, WkvT, WoutT, convWT,
                                        out + 4194304);

    // merged conv + KV(+Vt) + Q GEMMs (conv writes new_cmem before attn clobbers kvin)
    gemm_fused<<<1472, 256, 0, stream>>>(kvin, WqT, WkvT, convWT,
                                         Qb, KVb, Vtb, out + 8388608, convb);

    attn_fused10<<<dim3(1536), 256, 0, stream>>>(Qb, KVb, Vtb, peb, O01, lsep, attn);
    attn_combine<<<2048, 256, 0, stream>>>(O01, lsep, attn);

    // logits = attn_out @ Wout + b_out
    gemm_bt<<<256, 256, 0, stream>>>(attn, WoutT, out, bout, 1024);
    // aux_loss = 0
    hipMemsetAsync(out + 9437184, 0, 4, stream);
}

// Round 19
// 261.440 us; speedup vs baseline: 1.1026x; 1.1026x over previous
//
#include <hip/hip_runtime.h>

typedef unsigned short u16;
typedef unsigned int   u32;
typedef __bf16 bf16x8 __attribute__((ext_vector_type(8)));
typedef float  f32x4  __attribute__((ext_vector_type(4)));

__device__ __forceinline__ u16 f2bf(float f) {
    u32 u = __builtin_bit_cast(u32, f);
    u32 r = (u + 0x7FFFu + ((u >> 16) & 1u)) >> 16;
    return (u16)r;
}
__device__ __forceinline__ u32 pk2bf(float lo, float hi) {
    return (u32)f2bf(lo) | ((u32)f2bf(hi) << 16);
}
__device__ __forceinline__ float bf2f(u16 v) {
    return __builtin_bit_cast(float, (u32)v << 16);
}
__device__ __forceinline__ float fexp2(float x) { return __builtin_amdgcn_exp2f(x); }
__device__ __forceinline__ float flog2(float x) { return __builtin_amdgcn_logf(x); }
__device__ __forceinline__ f32x4 mfma16(bf16x8 a, bf16x8 b, f32x4 c) {
    return __builtin_amdgcn_mfma_f32_16x16x32_bf16(a, b, c, 0, 0, 0);
}
__device__ __forceinline__ bf16x8 ld8(const u16* p) {
    return __builtin_bit_cast(bf16x8, *(const uint4*)p);
}
__device__ __forceinline__ void gload_lds16(const u16* g, u16* l) {
    __builtin_amdgcn_global_load_lds(
        (__attribute__((address_space(1))) void*)g,
        (__attribute__((address_space(3))) void*)l, 16, 0, 0);
}

// ---------------- fused prep: kvin + new_mem copy + pos cvt + transposes + convw ----------------
__global__ void prep_all(const float* __restrict__ x, const float* __restrict__ mem,
                         const float* __restrict__ cmem, const float* __restrict__ pos,
                         const float* __restrict__ Wq, const float* __restrict__ Wkv,
                         const float* __restrict__ Wout, const float* __restrict__ convw,
                         u16* __restrict__ kvin, u16* __restrict__ peb,
                         u16* __restrict__ WqT, u16* __restrict__ WkvT,
                         u16* __restrict__ WoutT, u16* __restrict__ convWT,
                         float* __restrict__ newmem) {
    __shared__ float tile[32][33];
    const int bid = blockIdx.x, tid = threadIdx.x;
    if (bid < 9216) {
        const size_t i = ((size_t)bid * 256 + tid) * 4;
        const int row = (int)(i >> 10), col = (int)(i & 1023);
        const int b = row / 2304, j = row - b * 2304;
        const float* src;
        size_t xoff = 0;
        if (j < 256)       src = cmem + ((size_t)(b * 256  + j) << 10);
        else if (j < 1280) src = mem  + ((size_t)(b * 1024 + j - 256) << 10);
        else               { xoff = ((size_t)(b * 1024 + j - 1280) << 10); src = x + xoff; }
        float4 v = *(const float4*)(src + col);
        uint2 o;
        o.x = (u32)f2bf(v.x) | ((u32)f2bf(v.y) << 16);
        o.y = (u32)f2bf(v.z) | ((u32)f2bf(v.w) << 16);
        *(uint2*)(kvin + i) = o;
        if (j >= 1280) *(float4*)(newmem + xoff + col) = v;   // new_mem = x, fused
    } else if (bid < 11520) {
        const int i = ((bid - 9216) * 256 + tid) * 4;
        float4 v = *(const float4*)(pos + i);
        uint2 o;
        o.x = (u32)f2bf(v.x) | ((u32)f2bf(v.y) << 16);
        o.y = (u32)f2bf(v.z) | ((u32)f2bf(v.w) << 16);
        *(uint2*)(peb + i) = o;
    } else if (bid < 15616) {
        const float* in; u16* out; int K, N, bx, by;
        if (bid < 12544)      { in = Wq;   out = WqT;   K = 1024; N = 1024;
                                const int t = bid - 11520; bx = t & 31, by = t >> 5; }
        else if (bid < 14592) { in = Wkv;  out = WkvT;  K = 1024; N = 2048;
                                const int t = bid - 12544; bx = t & 63, by = t >> 6; }
        else                  { in = Wout; out = WoutT; K = 1024; N = 1024;
                                const int t = bid - 14592; bx = t & 31, by = t >> 5; }
        const int tx = tid & 31, ty = tid >> 5;
        #pragma unroll
        for (int i = 0; i < 32; i += 8)
            tile[ty + i][tx] = in[(size_t)(by * 32 + ty + i) * N + bx * 32 + tx];
        __syncthreads();
        #pragma unroll
        for (int i = 0; i < 32; i += 8)
            out[(size_t)(bx * 32 + ty + i) * K + by * 32 + tx] = f2bf(tile[tx][ty + i]);
    } else {
        const int o = bid - 15616;
        const float* src = convw + (size_t)o * 4096;
        u16* dst = convWT + (size_t)o * 4096;
        #pragma unroll
        for (int it = 0; it < 4; ++it) {
            const int d = it * 256 + tid;
            float4 v = *(const float4*)(src + d * 4);
            dst[d]        = f2bf(v.x);
            dst[1024 + d] = f2bf(v.y);
            dst[2048 + d] = f2bf(v.z);
            dst[3072 + d] = f2bf(v.w);
        }
    }
}

// ---------------- merged conv/KV/Q GEMM: BK=64, XOR-swizzled staging ----------------
// Per kt: 8 gload_lds (16B each), halved barrier count vs BK=32.
// LDS [row][64] with col8 ^= row&7: frag reads 2-way conflict (free).
__global__ __launch_bounds__(256)
void gemm_fused(const u16* __restrict__ kvin, const u16* __restrict__ WqT,
                const u16* __restrict__ WkvT, const u16* __restrict__ convWT,
                u16* __restrict__ Qb, u16* __restrict__ KVb, u16* __restrict__ Vtb,
                float* __restrict__ convOut, const float* __restrict__ convb) {
    __shared__ __align__(16) u16 sh[16384];   // 32KB: As|Bs staging; V-transpose reuses
    u16* As = sh;
    u16* Bs = sh + 128 * 64;
    const int bid = blockIdx.x, tid = threadIdx.x;
    int seg, local;
    if (bid < 64)        { seg = 2; local = bid; }          // conv (K=4096) first
    else if (bid < 1216) { seg = 1; local = bid - 64; }     // KV
    else                 { seg = 0; local = bid - 1216; }   // Q
    const int xcd = local & 7, idx = local >> 3;
    int m0, n0;
    const u16* BT; int N, K, rowblk, rowstride, rowoff;
    if (seg == 0) {
        m0 = (xcd * 4 + (idx & 3)) * 128; n0 = (idx >> 2) * 128;
        BT = WqT;    N = 1024; K = 1024; rowblk = 1024; rowstride = 2304; rowoff = 1280;
    } else if (seg == 1) {
        m0 = (xcd * 9 + idx % 9) * 128;   n0 = (idx / 9) * 128;
        BT = WkvT;   N = 2048; K = 1024; rowblk = 9216; rowstride = 0;    rowoff = 0;
    } else {
        m0 = ((xcd & 3) * 2 + (idx & 1)) * 128; n0 = ((xcd >> 2) * 4 + (idx >> 1)) * 128;
        BT = convWT; N = 1024; K = 4096; rowblk = 256;  rowstride = 576;  rowoff = 64;
    }

    const int wv = tid >> 6, lane = tid & 63;
    const int fr = lane & 15, fg = lane >> 4;
    const int wr = (wv >> 1) * 64, wc = (wv & 1) * 64;
    const int lrow = lane >> 3;                 // 0..7 (row within 8-row stripe)
    const int lcol8 = ((lane & 7) ^ lrow) * 8;  // inverse-swizzled source col (u16)

    size_t aoff[4], boff[4];
    #pragma unroll
    for (int i = 0; i < 4; ++i) {
        const int ag = m0 + wv * 32 + i * 8 + lrow;
        const size_t arow = (size_t)(ag / rowblk) * rowstride + (ag % rowblk) + rowoff;
        aoff[i] = arow * K + lcol8;
        const int bg = n0 + wv * 32 + i * 8 + lrow;
        boff[i] = (size_t)bg * K + lcol8;
    }

    f32x4 acc[4][4] = {};
    const int nk = K / 64;
    for (int kt = 0; kt < nk; ++kt) {
        __syncthreads();
        #pragma unroll
        for (int i = 0; i < 4; ++i)
            gload_lds16(kvin + aoff[i] + kt * 64, As + wv * 2048 + i * 512);
        #pragma unroll
        for (int i = 0; i < 4; ++i)
            gload_lds16(BT + boff[i] + kt * 64, Bs + wv * 2048 + i * 512);
        __syncthreads();
        #pragma unroll
        for (int ks = 0; ks < 2; ++ks) {
            bf16x8 af[4], bfv[4];
            #pragma unroll
            for (int i = 0; i < 4; ++i) {
                const int row = wr + i * 16 + fr;
                af[i] = ld8(As + row * 64 + (((ks * 4 + fg) ^ (row & 7)) * 8));
            }
            #pragma unroll
            for (int i = 0; i < 4; ++i) {
                const int row = wc + i * 16 + fr;
                bfv[i] = ld8(Bs + row * 64 + (((ks * 4 + fg) ^ (row & 7)) * 8));
            }
            #pragma unroll
            for (int mi = 0; mi < 4; ++mi)
                #pragma unroll
                for (int ni = 0; ni < 4; ++ni)
                    acc[mi][ni] = mfma16(af[mi], bfv[ni], acc[mi][ni]);
        }
    }
    if (seg == 1 && n0 >= 1024) {
        const int bb = m0 / 2304;
        const int j0 = m0 - bb * 2304;
        const int c0 = n0 - 1024;
        #pragma unroll
        for (int p = 0; p < 2; ++p) {
            __syncthreads();
            if ((wv & 1) == p) {
                #pragma unroll
                for (int mi = 0; mi < 4; ++mi)
                    #pragma unroll
                    for (int ni = 0; ni < 4; ++ni)
                        #pragma unroll
                        for (int r = 0; r < 4; ++r)
                            sh[(ni * 16 + fr) * 136 + wr + mi * 16 + fg * 4 + r]
                                = f2bf(acc[mi][ni][r]);
            }
            __syncthreads();
            #pragma unroll
            for (int it = 0; it < 2; ++it) {
                const int idx2 = it * 256 + tid;
                const int d = idx2 >> 3, jo = (idx2 & 7) * 16;
                *(uint4*)(Vtb + ((size_t)(bb * 1024 + c0 + p * 64 + d)) * 2304 + j0 + jo)
                    = *(const uint4*)(sh + d * 136 + jo);
            }
        }
        return;
    }
    #pragma unroll
    for (int mi = 0; mi < 4; ++mi) {
        #pragma unroll
        for (int ni = 0; ni < 4; ++ni) {
            const int col = n0 + wc + ni * 16 + fr;
            const float bv = (seg == 2) ? convb[col] : 0.0f;
            #pragma unroll
            for (int r = 0; r < 4; ++r) {
                const int row = m0 + wr + mi * 16 + fg * 4 + r;
                const float v = acc[mi][ni][r] + bv;
                if (seg == 2)      convOut[(size_t)row * 1024 + col] = v;
                else if (seg == 0) Qb[(size_t)row * 1024 + col] = f2bf(v);
                else               KVb[(size_t)row * 2048 + col] = f2bf(v);
            }
        }
    }
}

// ---------------- Wout GEMM (BK=64 swizzled, XCD m-chunk, 1D grid 256) ----------------
__global__ __launch_bounds__(256)
void gemm_bt(const u16* __restrict__ A, const u16* __restrict__ BT,
             float* __restrict__ Cf, const float* __restrict__ bias, int K) {
    __shared__ __align__(16) u16 sh[16384];
    u16* As = sh;
    u16* Bs = sh + 128 * 64;
    const int tid = threadIdx.x;
    const int xcd = blockIdx.x & 7, idx = blockIdx.x >> 3;
    const int m0 = (xcd * 4 + (idx & 3)) * 128, n0 = (idx >> 2) * 128;
    const int wv = tid >> 6, lane = tid & 63;
    const int fr = lane & 15, fg = lane >> 4;
    const int wr = (wv >> 1) * 64, wc = (wv & 1) * 64;
    const int lrow = lane >> 3;
    const int lcol8 = ((lane & 7) ^ lrow) * 8;
    size_t aoff[4], boff[4];
    #pragma unroll
    for (int i = 0; i < 4; ++i) {
        const int ag = m0 + wv * 32 + i * 8 + lrow;
        aoff[i] = (size_t)ag * K + lcol8;
        const int bg = n0 + wv * 32 + i * 8 + lrow;
        boff[i] = (size_t)bg * K + lcol8;
    }
    f32x4 acc[4][4] = {};
    const int nk = K / 64;
    for (int kt = 0; kt < nk; ++kt) {
        __syncthreads();
        #pragma unroll
        for (int i = 0; i < 4; ++i)
            gload_lds16(A + aoff[i] + kt * 64, As + wv * 2048 + i * 512);
        #pragma unroll
        for (int i = 0; i < 4; ++i)
            gload_lds16(BT + boff[i] + kt * 64, Bs + wv * 2048 + i * 512);
        __syncthreads();
        #pragma unroll
        for (int ks = 0; ks < 2; ++ks) {
            bf16x8 af[4], bfv[4];
            #pragma unroll
            for (int i = 0; i < 4; ++i) {
                const int row = wr + i * 16 + fr;
                af[i] = ld8(As + row * 64 + (((ks * 4 + fg) ^ (row & 7)) * 8));
            }
            #pragma unroll
            for (int i = 0; i < 4; ++i) {
                const int row = wc + i * 16 + fr;
                bfv[i] = ld8(Bs + row * 64 + (((ks * 4 + fg) ^ (row & 7)) * 8));
            }
            #pragma unroll
            for (int mi = 0; mi < 4; ++mi)
                #pragma unroll
                for (int ni = 0; ni < 4; ++ni)
                    acc[mi][ni] = mfma16(af[mi], bfv[ni], acc[mi][ni]);
        }
    }
    #pragma unroll
    for (int mi = 0; mi < 4; ++mi) {
        #pragma unroll
        for (int ni = 0; ni < 4; ++ni) {
            const int col = n0 + wc + ni * 16 + fr;
            const float bv = bias[col];
            #pragma unroll
            for (int r = 0; r < 4; ++r) {
                const int row = m0 + wr + mi * 16 + fg * 4 + r;
                Cf[(size_t)row * 1024 + col] = acc[mi][ni][r] + bv;
            }
        }
    }
}

// ---------------- fused attention (R13-proven): swapped softmax, b64 sc, 3-barrier pipeline ----------------
__global__ __launch_bounds__(256, 2)
void attn_fused10(const u16* __restrict__ Qb, const u16* __restrict__ KVb,
                  const u16* __restrict__ Vtb, const u16* __restrict__ peb,
                  u16* __restrict__ O01, float* __restrict__ lsep,
                  u16* __restrict__ O2) {
    const int bid = blockIdx.x;
    const int xcd = bid & 7, ii = bid >> 3;
    const int G = xcd * 12 + (ii >> 4), qt = ii & 15;
    const int b = G / 24, rem = G - b * 24;
    const int h = rem / 3, sp = rem - (rem / 3) * 3;

    const int tid = threadIdx.x, w = tid >> 6, lane = tid & 63;
    const int fr = lane & 15, fg = lane >> 4;
    const int q0 = qt * 64, q0w = q0 + w * 16;
    const int n64 = min(2304, q0 + 1344) >> 6;
    const int base = n64 / 3, rm = n64 - base * 3;
    const int cbeg = sp * base + min(sp, rm);
    const int cnt = base + (sp < rm ? 1 : 0);
    const int kbeg = cbeg << 6, kend = (cbeg + cnt) << 6;

    __shared__ __align__(16) u16 Ks[64 * 128];
    __shared__ __align__(16) u16 Vs[128 * 64];
    __shared__ __align__(16) u16 PEs[2][64 * 128];
    __shared__ __align__(16) u16 sc[4][16][108];

    const u16* kvbase = KVb + (size_t)b * 2304 * 2048 + h * 128;
    const u16* vtbase = Vtb + (size_t)(b * 8 + h) * 128 * 2304;
    const u16* pebase = peb + (size_t)h * 2304 * 128;
    const float scale2 = 0.088388347648318447f * 1.4426950408889634f;

    bf16x8 qf[4];
    {
        const u16* qp = Qb + (size_t)(b * 1024 + q0w + fr) * 1024 + h * 128 + fg * 8;
        #pragma unroll
        for (int dc = 0; dc < 4; ++dc) qf[dc] = ld8(qp + dc * 32);
    }

    const u16* srcK[4];
    const u16* srcV[4];
    const u16* srcP[4];
    #pragma unroll
    for (int i = 0; i < 4; ++i) {
        const int kr = w * 16 + i * 4 + (lane >> 4);
        srcK[i] = kvbase + (size_t)kr * 2048 + (((lane & 15) ^ (kr & 7)) * 8);
        srcP[i] = pebase + (size_t)kr * 128  + (((lane & 15) ^ (kr & 7)) * 8);
        const int vr = w * 32 + i * 8 + (lane >> 3);
        srcV[i] = vtbase + (size_t)vr * 2304 + (((lane & 7) ^ (vr & 7)) * 8);
    }

    // prologue: stage K, V, PE-lo, PE-hi for chunk kbeg
    {
        const int cc0 = (kbeg - q0) >> 6;
        u16* lo = &PEs[(cc0 + 15) & 1][0];
        u16* up = &PEs[(cc0 + 16) & 1][0];
        const size_t jlo = (size_t)(kbeg - q0 + 960) * 128;
        const size_t jup = (size_t)(kbeg - q0 + 1024) * 128;
        #pragma unroll
        for (int i = 0; i < 4; ++i)
            gload_lds16(srcK[i] + (size_t)kbeg * 2048, Ks + w * 2048 + i * 512);
        #pragma unroll
        for (int i = 0; i < 4; ++i)
            gload_lds16(srcV[i] + kbeg, &Vs[0] + w * 2048 + i * 512);
        #pragma unroll
        for (int i = 0; i < 4; ++i)
            gload_lds16(srcP[i] + jlo, lo + w * 2048 + i * 512);
        #pragma unroll
        for (int i = 0; i < 4; ++i)
            gload_lds16(srcP[i] + jup, up + w * 2048 + i * 512);
    }

    f32x4 o[8] = {};
    float mrow = -1e30f, lrow = 0.0f;   // per-lane, q = q0w + fr

    for (int k0 = kbeg; k0 < kend; k0 += 64) {
        const int cc = (k0 - q0) >> 6;
        const bool more = (k0 + 64 < kend);
        __syncthreads();   // B1: drain staged loads

        // ---- S^T = K Q^T + PE^T band, LDS-fed, swapped args ----
        __builtin_amdgcn_s_setprio(1);
        f32x4 s[4] = {};
        #pragma unroll
        for (int kb = 0; kb < 4; ++kb) {
            const int row = kb * 16 + fr;
            #pragma unroll
            for (int dc = 0; dc < 4; ++dc) {
                bf16x8 kf = ld8(Ks + row * 128 + ((dc * 32 + fg * 8) ^ ((row & 7) << 3)));
                s[kb] = mfma16(kf, qf[dc], s[kb]);
            }
        }
        const u16* pl = &PEs[(cc + 15) & 1][0];
        const u16* pu = &PEs[(cc + 16) & 1][0];
        f32x4 pp[5] = {};
        #pragma unroll
        for (int jb = 0; jb < 5; ++jb) {
            const int lstart = 48 - 16 * w + 16 * jb;
            const u16* pbase = (lstart < 64) ? (pl + lstart * 128) : (pu + (lstart - 64) * 128);
            #pragma unroll
            for (int dc = 0; dc < 4; ++dc) {
                bf16x8 pf = ld8(pbase + fr * 128 + ((dc * 32 + fg * 8) ^ ((fr & 7) << 3)));
                pp[jb] = mfma16(pf, qf[dc], pp[jb]);
            }
        }
        __builtin_amdgcn_s_setprio(0);
        #pragma unroll
        for (int jb = 0; jb < 5; ++jb) {
            uint2 pk;
            pk.x = pk2bf(pp[jb][0], pp[jb][1]);
            pk.y = pk2bf(pp[jb][2], pp[jb][3]);
            *(uint2*)(&sc[w][fr][jb * 16 + fg * 4]) = pk;
        }
        asm volatile("s_waitcnt lgkmcnt(0)" ::: "memory");

        __syncthreads();   // B2: Ks/PEs reads complete -> safe to restage

        if (more) {
            #pragma unroll
            for (int i = 0; i < 4; ++i)
                gload_lds16(srcK[i] + (size_t)(k0 + 64) * 2048, Ks + w * 2048 + i * 512);
            u16* pslot = &PEs[(cc + 15) & 1][0];
            const size_t jnext = (size_t)(k0 - q0 + 1088) * 128;
            #pragma unroll
            for (int i = 0; i < 4; ++i)
                gload_lds16(srcP[i] + jnext, pslot + w * 2048 + i * 512);
        }

        // ---- combine + mask + online softmax: q = fr, k = k0 + kb*16 + fg*4 + r ----
        const bool need_mask = (k0 + 63) > (q0w + 1280);
        float pv[4][4];
        float mx = mrow;
        #pragma unroll
        for (int kb = 0; kb < 4; ++kb) {
            #pragma unroll
            for (int r = 0; r < 4; ++r) {
                float v = (s[kb][r] + bf2f(sc[w][fr][kb * 16 + fg * 4 + r + 15 - fr])) * scale2;
                if (need_mask && (k0 + kb * 16 + fg * 4 + r) > (q0w + fr + 1280)) v = -1e30f;
                pv[kb][r] = v;
                mx = fmaxf(mx, v);
            }
        }
        mx = fmaxf(mx, __shfl_xor(mx, 16));
        mx = fmaxf(mx, __shfl_xor(mx, 32));
        if (!__all(mx - mrow <= 8.0f)) {
            const float alpha = fexp2(mrow - mx);
            mrow = mx;
            lrow *= alpha;
            float a4[4];
            #pragma unroll
            for (int r = 0; r < 4; ++r) a4[r] = __shfl(alpha, fg * 4 + r);
            #pragma unroll
            for (int db = 0; db < 8; ++db)
                #pragma unroll
                for (int r = 0; r < 4; ++r) o[db][r] *= a4[r];
        }
        float rsum = 0.0f;
        #pragma unroll
        for (int kb = 0; kb < 4; ++kb)
            #pragma unroll
            for (int r = 0; r < 4; ++r) {
                const float p = fexp2(pv[kb][r] - mrow);
                pv[kb][r] = p;
                rsum += p;
            }
        rsum += __shfl_xor(rsum, 16);
        rsum += __shfl_xor(rsum, 32);
        lrow += rsum;
        #pragma unroll
        for (int kb = 0; kb < 4; ++kb) {
            uint2 pk;
            pk.x = pk2bf(pv[kb][0], pv[kb][1]);
            pk.y = pk2bf(pv[kb][2], pv[kb][3]);
            *(uint2*)(&sc[w][fr][kb * 16 + fg * 4]) = pk;
        }
        asm volatile("s_waitcnt lgkmcnt(0)" ::: "memory");
        // ---- O += P V ----
        __builtin_amdgcn_s_setprio(1);
        #pragma unroll
        for (int ks = 0; ks < 2; ++ks) {
            bf16x8 pa = __builtin_bit_cast(bf16x8, *(const uint4*)(&sc[w][fr][ks * 32 + fg * 8]));
            #pragma unroll
            for (int db = 0; db < 8; ++db) {
                const int d = db * 16 + fr;
                bf16x8 vf = ld8(Vs + d * 64 + ((ks * 32 + fg * 8) ^ ((d & 7) << 3)));
                o[db] = mfma16(pa, vf, o[db]);
            }
        }
        __builtin_amdgcn_s_setprio(0);

        __syncthreads();   // B3: Vs reads complete

        if (more) {
            #pragma unroll
            for (int i = 0; i < 4; ++i)
                gload_lds16(srcV[i] + (k0 + 64), &Vs[0] + w * 2048 + i * 512);
        }
    }
    // ---- epilogue: normalized partial + lse (log2 domain) ----
    const float inv = 1.0f / lrow;
    float inv4[4];
    #pragma unroll
    for (int r = 0; r < 4; ++r) inv4[r] = __shfl(inv, fg * 4 + r);
    u16* dst = (sp == 2) ? O2 : (O01 + (size_t)sp * 4194304);
    #pragma unroll
    for (int db = 0; db < 8; ++db)
        #pragma unroll
        for (int r = 0; r < 4; ++r)
            dst[(size_t)(b * 1024 + q0w + fg * 4 + r) * 1024 + h * 128 + db * 16 + fr]
                = f2bf(o[db][r] * inv4[r]);
    if (lane < 16)
        lsep[sp * 32768 + (b * 8 + h) * 1024 + q0w + lane] = mrow + flog2(lrow);
}

// combine 3 flash partials (lse in log2 domain)
__global__ void attn_combine(const u16* __restrict__ O01, const float* __restrict__ lsep,
                             u16* __restrict__ O2) {
    const int i = (blockIdx.x * 256 + threadIdx.x) * 8;
    const int row = i >> 10;
    const int b = row >> 10, q = row & 1023;
    const int h = (i & 1023) >> 7;
    const int li = (b * 8 + h) * 1024 + q;
    const float l0 = lsep[li], l1 = lsep[li + 32768], l2 = lsep[li + 65536];
    const float M = fmaxf(l0, fmaxf(l1, l2));
    const float w0 = fexp2(l0 - M), w1 = fexp2(l1 - M), w2 = fexp2(l2 - M);
    const float inv = 1.0f / (w0 + w1 + w2);
    uint4 a = *(const uint4*)(O01 + i);
    uint4 c = *(const uint4*)(O01 + 4194304 + i);
    uint4 e = *(const uint4*)(O2 + i);
    const u16* ap = (const u16*)&a;
    const u16* cp = (const u16*)&c;
    const u16* ep = (const u16*)&e;
    u16 ov[8];
    #pragma unroll
    for (int j = 0; j < 8; ++j)
        ov[j] = f2bf((w0 * bf2f(ap[j]) + w1 * bf2f(cp[j]) + w2 * bf2f(ep[j])) * inv);
    *(uint4*)(O2 + i) = *(const uint4*)ov;
}

// ---------------- launch ----------------

extern "C" void kernel_launch(void* const* d_in, const int* in_sizes, int n_in,
                              void* d_out, int out_size, void* d_ws, size_t ws_size,
                              hipStream_t stream) {
    const float* x     = (const float*)d_in[0];
    const float* mem   = (const float*)d_in[1];
    const float* cmem  = (const float*)d_in[2];
    const float* pos   = (const float*)d_in[3];
    const float* Wq    = (const float*)d_in[5];
    const float* Wkv   = (const float*)d_in[6];
    const float* Wout  = (const float*)d_in[7];
    const float* bout  = (const float*)d_in[8];
    const float* convw = (const float*)d_in[9];
    const float* convb = (const float*)d_in[10];
    float* out = (float*)d_out;

    u16* ws = (u16*)d_ws;
    size_t off = 0;
    u16* kvin   = ws + off; off += (size_t)9216 * 1024;   // also reused as O-partials
    u16* WqT    = ws + off; off += (size_t)1024 * 1024;
    u16* WkvT   = ws + off; off += (size_t)2048 * 1024;
    u16* WoutT  = ws + off; off += (size_t)1024 * 1024;
    u16* convWT = ws + off; off += (size_t)1024 * 4096;
    u16* peb    = ws + off; off += (size_t)8 * 2304 * 128;
    u16* Qb     = ws + off; off += (size_t)4096 * 1024;
    u16* KVb    = ws + off; off += (size_t)9216 * 2048;
    u16* Vtb    = ws + off; off += (size_t)4 * 8 * 128 * 2304;
    u16* attn   = ws + off; off += (size_t)4096 * 1024;

    u16* O01 = kvin;                             // splits 0,1: 2 x 4194304 u16
    float* lsep = (float*)(kvin + 8388608);      // 3 x 32768 f32

    prep_all<<<16640, 256, 0, stream>>>(x, mem, cmem, pos, Wq, Wkv, Wout, convw,
                                        kvin, peb, WqT, WkvT, WoutT, convWT,
                                        out + 4194304);

    // merged conv + KV(+Vt) + Q GEMMs (conv writes new_cmem before attn clobbers kvin)
    gemm_fused<<<1472, 256, 0, stream>>>(kvin, WqT, WkvT, convWT,
                                         Qb, KVb, Vtb, out + 8388608, convb);

    attn_fused10<<<dim3(1536), 256, 0, stream>>>(Qb, KVb, Vtb, peb, O01, lsep, attn);
    attn_combine<<<2048, 256, 0, stream>>>(O01, lsep, attn);

    // logits = attn_out @ Wout + b_out
    gemm_bt<<<256, 256, 0, stream>>>(attn, WoutT, out, bout, 1024);
    // aux_loss = 0
    hipMemsetAsync(out + 9437184, 0, 4, stream);
}

// Round 20
// 260.334 us; speedup vs baseline: 1.1072x; 1.0042x over previous
//
#include <hip/hip_runtime.h>

typedef unsigned short u16;
typedef unsigned int   u32;
typedef __bf16 bf16x8 __attribute__((ext_vector_type(8)));
typedef float  f32x4  __attribute__((ext_vector_type(4)));

__device__ __forceinline__ u16 f2bf(float f) {
    u32 u = __builtin_bit_cast(u32, f);
    u32 r = (u + 0x7FFFu + ((u >> 16) & 1u)) >> 16;
    return (u16)r;
}
__device__ __forceinline__ u32 pk2bf(float lo, float hi) {
    return (u32)f2bf(lo) | ((u32)f2bf(hi) << 16);
}
__device__ __forceinline__ float bf2f(u16 v) {
    return __builtin_bit_cast(float, (u32)v << 16);
}
__device__ __forceinline__ float fexp2(float x) { return __builtin_amdgcn_exp2f(x); }
__device__ __forceinline__ float flog2(float x) { return __builtin_amdgcn_logf(x); }
__device__ __forceinline__ f32x4 mfma16(bf16x8 a, bf16x8 b, f32x4 c) {
    return __builtin_amdgcn_mfma_f32_16x16x32_bf16(a, b, c, 0, 0, 0);
}
__device__ __forceinline__ bf16x8 ld8(const u16* p) {
    return __builtin_bit_cast(bf16x8, *(const uint4*)p);
}
__device__ __forceinline__ void gload_lds16(const u16* g, u16* l) {
    __builtin_amdgcn_global_load_lds(
        (__attribute__((address_space(1))) void*)g,
        (__attribute__((address_space(3))) void*)l, 16, 0, 0);
}

// ---------------- fused prep: kvin + new_mem copy + pos cvt + transposes + convw ----------------
__global__ void prep_all(const float* __restrict__ x, const float* __restrict__ mem,
                         const float* __restrict__ cmem, const float* __restrict__ pos,
                         const float* __restrict__ Wq, const float* __restrict__ Wkv,
                         const float* __restrict__ Wout, const float* __restrict__ convw,
                         u16* __restrict__ kvin, u16* __restrict__ peb,
                         u16* __restrict__ WqT, u16* __restrict__ WkvT,
                         u16* __restrict__ WoutT, u16* __restrict__ convWT,
                         float* __restrict__ newmem) {
    __shared__ float tile[32][33];
    const int bid = blockIdx.x, tid = threadIdx.x;
    if (bid < 9216) {
        const size_t i = ((size_t)bid * 256 + tid) * 4;
        const int row = (int)(i >> 10), col = (int)(i & 1023);
        const int b = row / 2304, j = row - b * 2304;
        const float* src;
        size_t xoff = 0;
        if (j < 256)       src = cmem + ((size_t)(b * 256  + j) << 10);
        else if (j < 1280) src = mem  + ((size_t)(b * 1024 + j - 256) << 10);
        else               { xoff = ((size_t)(b * 1024 + j - 1280) << 10); src = x + xoff; }
        float4 v = *(const float4*)(src + col);
        uint2 o;
        o.x = (u32)f2bf(v.x) | ((u32)f2bf(v.y) << 16);
        o.y = (u32)f2bf(v.z) | ((u32)f2bf(v.w) << 16);
        *(uint2*)(kvin + i) = o;
        if (j >= 1280) *(float4*)(newmem + xoff + col) = v;   // new_mem = x, fused
    } else if (bid < 11520) {
        const int i = ((bid - 9216) * 256 + tid) * 4;
        float4 v = *(const float4*)(pos + i);
        uint2 o;
        o.x = (u32)f2bf(v.x) | ((u32)f2bf(v.y) << 16);
        o.y = (u32)f2bf(v.z) | ((u32)f2bf(v.w) << 16);
        *(uint2*)(peb + i) = o;
    } else if (bid < 15616) {
        const float* in; u16* out; int K, N, bx, by;
        if (bid < 12544)      { in = Wq;   out = WqT;   K = 1024; N = 1024;
                                const int t = bid - 11520; bx = t & 31, by = t >> 5; }
        else if (bid < 14592) { in = Wkv;  out = WkvT;  K = 1024; N = 2048;
                                const int t = bid - 12544; bx = t & 63, by = t >> 6; }
        else                  { in = Wout; out = WoutT; K = 1024; N = 1024;
                                const int t = bid - 14592; bx = t & 31, by = t >> 5; }
        const int tx = tid & 31, ty = tid >> 5;
        #pragma unroll
        for (int i = 0; i < 32; i += 8)
            tile[ty + i][tx] = in[(size_t)(by * 32 + ty + i) * N + bx * 32 + tx];
        __syncthreads();
        #pragma unroll
        for (int i = 0; i < 32; i += 8)
            out[(size_t)(bx * 32 + ty + i) * K + by * 32 + tx] = f2bf(tile[tx][ty + i]);
    } else {
        const int o = bid - 15616;
        const float* src = convw + (size_t)o * 4096;
        u16* dst = convWT + (size_t)o * 4096;
        #pragma unroll
        for (int it = 0; it < 4; ++it) {
            const int d = it * 256 + tid;
            float4 v = *(const float4*)(src + d * 4);
            dst[d]        = f2bf(v.x);
            dst[1024 + d] = f2bf(v.y);
            dst[2048 + d] = f2bf(v.z);
            dst[3072 + d] = f2bf(v.w);
        }
    }
}

// ---------------- merged conv/KV/Q GEMM: BK=64 swizzled, conv split-K x4 (uniform 16-iter blocks) ----------------
// seg2: conv partials (256 blocks = 64 tiles x 4 ksplits) -> convPart (bf16)
// seg1: KV + V->Vt (1152)   seg0: Q (256)
__global__ __launch_bounds__(256)
void gemm_fused(const u16* __restrict__ kvin, const u16* __restrict__ WqT,
                const u16* __restrict__ WkvT, const u16* __restrict__ convWT,
                u16* __restrict__ Qb, u16* __restrict__ KVb, u16* __restrict__ Vtb,
                u16* __restrict__ convPart) {
    __shared__ __align__(16) u16 sh[16384];   // 32KB: As|Bs staging; V-transpose reuses
    u16* As = sh;
    u16* Bs = sh + 128 * 64;
    const int bid = blockIdx.x, tid = threadIdx.x;
    int seg, local;
    if (bid < 256)       { seg = 2; local = bid; }          // conv split-K first
    else if (bid < 1408) { seg = 1; local = bid - 256; }    // KV
    else                 { seg = 0; local = bid - 1408; }   // Q
    const int xcd = local & 7, idx = local >> 3;
    int m0, n0, kk = 0;
    const u16* BT; int N, K, rowblk, rowstride, rowoff;
    if (seg == 0) {
        m0 = (xcd * 4 + (idx & 3)) * 128; n0 = (idx >> 2) * 128;
        BT = WqT;    N = 1024; K = 1024; rowblk = 1024; rowstride = 2304; rowoff = 1280;
    } else if (seg == 1) {
        m0 = (xcd * 9 + idx % 9) * 128;   n0 = (idx / 9) * 128;
        BT = WkvT;   N = 2048; K = 1024; rowblk = 9216; rowstride = 0;    rowoff = 0;
    } else {
        kk = idx >> 3;                      // 0..3 K-split
        const int t = idx & 7;              // tile within XCD
        m0 = ((xcd & 3) * 2 + (t & 1)) * 128; n0 = ((xcd >> 2) * 4 + (t >> 1)) * 128;
        BT = convWT; N = 1024; K = 4096; rowblk = 256;  rowstride = 576;  rowoff = 64;
    }
    const int kbase = kk * 1024;

    const int wv = tid >> 6, lane = tid & 63;
    const int fr = lane & 15, fg = lane >> 4;
    const int wr = (wv >> 1) * 64, wc = (wv & 1) * 64;
    const int lrow = lane >> 3;                 // 0..7 (row within 8-row stripe)
    const int lcol8 = ((lane & 7) ^ lrow) * 8;  // inverse-swizzled source col (u16)

    size_t aoff[4], boff[4];
    #pragma unroll
    for (int i = 0; i < 4; ++i) {
        const int ag = m0 + wv * 32 + i * 8 + lrow;
        const size_t arow = (size_t)(ag / rowblk) * rowstride + (ag % rowblk) + rowoff;
        aoff[i] = arow * K + kbase + lcol8;
        const int bg = n0 + wv * 32 + i * 8 + lrow;
        boff[i] = (size_t)bg * K + kbase + lcol8;
    }

    f32x4 acc[4][4] = {};
    for (int kt = 0; kt < 16; ++kt) {
        __syncthreads();
        #pragma unroll
        for (int i = 0; i < 4; ++i)
            gload_lds16(kvin + aoff[i] + kt * 64, As + wv * 2048 + i * 512);
        #pragma unroll
        for (int i = 0; i < 4; ++i)
            gload_lds16(BT + boff[i] + kt * 64, Bs + wv * 2048 + i * 512);
        __syncthreads();
        #pragma unroll
        for (int ks = 0; ks < 2; ++ks) {
            bf16x8 af[4], bfv[4];
            #pragma unroll
            for (int i = 0; i < 4; ++i) {
                const int row = wr + i * 16 + fr;
                af[i] = ld8(As + row * 64 + (((ks * 4 + fg) ^ (row & 7)) * 8));
            }
            #pragma unroll
            for (int i = 0; i < 4; ++i) {
                const int row = wc + i * 16 + fr;
                bfv[i] = ld8(Bs + row * 64 + (((ks * 4 + fg) ^ (row & 7)) * 8));
            }
            #pragma unroll
            for (int mi = 0; mi < 4; ++mi)
                #pragma unroll
                for (int ni = 0; ni < 4; ++ni)
                    acc[mi][ni] = mfma16(af[mi], bfv[ni], acc[mi][ni]);
        }
    }
    if (seg == 1 && n0 >= 1024) {
        const int bb = m0 / 2304;
        const int j0 = m0 - bb * 2304;
        const int c0 = n0 - 1024;
        #pragma unroll
        for (int p = 0; p < 2; ++p) {
            __syncthreads();
            if ((wv & 1) == p) {
                #pragma unroll
                for (int mi = 0; mi < 4; ++mi)
                    #pragma unroll
                    for (int ni = 0; ni < 4; ++ni)
                        #pragma unroll
                        for (int r = 0; r < 4; ++r)
                            sh[(ni * 16 + fr) * 136 + wr + mi * 16 + fg * 4 + r]
                                = f2bf(acc[mi][ni][r]);
            }
            __syncthreads();
            #pragma unroll
            for (int it = 0; it < 2; ++it) {
                const int idx2 = it * 256 + tid;
                const int d = idx2 >> 3, jo = (idx2 & 7) * 16;
                *(uint4*)(Vtb + ((size_t)(bb * 1024 + c0 + p * 64 + d)) * 2304 + j0 + jo)
                    = *(const uint4*)(sh + d * 136 + jo);
            }
        }
        return;
    }
    #pragma unroll
    for (int mi = 0; mi < 4; ++mi) {
        #pragma unroll
        for (int ni = 0; ni < 4; ++ni) {
            const int col = n0 + wc + ni * 16 + fr;
            #pragma unroll
            for (int r = 0; r < 4; ++r) {
                const int row = m0 + wr + mi * 16 + fg * 4 + r;
                const float v = acc[mi][ni][r];
                if (seg == 2)      convPart[(size_t)kk * 1048576 + (size_t)row * 1024 + col] = f2bf(v);
                else if (seg == 0) Qb[(size_t)row * 1024 + col] = f2bf(v);
                else               KVb[(size_t)row * 2048 + col] = f2bf(v);
            }
        }
    }
}

// ---------------- conv split-K combine: new_cmem = sum(4 partials) + bias ----------------
__global__ void conv_combine(const u16* __restrict__ P, const float* __restrict__ convb,
                             float* __restrict__ outp) {
    const int i = (blockIdx.x * 256 + threadIdx.x) * 4;
    const int col = i & 1023;
    uint2 a = *(const uint2*)(P + i);
    uint2 b = *(const uint2*)(P + 1048576 + i);
    uint2 c = *(const uint2*)(P + 2097152 + i);
    uint2 d = *(const uint2*)(P + 3145728 + i);
    const u16* ap = (const u16*)&a;
    const u16* bp = (const u16*)&b;
    const u16* cp = (const u16*)&c;
    const u16* dp = (const u16*)&d;
    float4 o;
    o.x = bf2f(ap[0]) + bf2f(bp[0]) + bf2f(cp[0]) + bf2f(dp[0]) + convb[col];
    o.y = bf2f(ap[1]) + bf2f(bp[1]) + bf2f(cp[1]) + bf2f(dp[1]) + convb[col + 1];
    o.z = bf2f(ap[2]) + bf2f(bp[2]) + bf2f(cp[2]) + bf2f(dp[2]) + convb[col + 2];
    o.w = bf2f(ap[3]) + bf2f(bp[3]) + bf2f(cp[3]) + bf2f(dp[3]) + convb[col + 3];
    *(float4*)(outp + i) = o;
}

// ---------------- Wout GEMM (BK=64 swizzled, XCD m-chunk, 1D grid 256) ----------------
__global__ __launch_bounds__(256)
void gemm_bt(const u16* __restrict__ A, const u16* __restrict__ BT,
             float* __restrict__ Cf, const float* __restrict__ bias, int K) {
    __shared__ __align__(16) u16 sh[16384];
    u16* As = sh;
    u16* Bs = sh + 128 * 64;
    const int tid = threadIdx.x;
    const int xcd = blockIdx.x & 7, idx = blockIdx.x >> 3;
    const int m0 = (xcd * 4 + (idx & 3)) * 128, n0 = (idx >> 2) * 128;
    const int wv = tid >> 6, lane = tid & 63;
    const int fr = lane & 15, fg = lane >> 4;
    const int wr = (wv >> 1) * 64, wc = (wv & 1) * 64;
    const int lrow = lane >> 3;
    const int lcol8 = ((lane & 7) ^ lrow) * 8;
    size_t aoff[4], boff[4];
    #pragma unroll
    for (int i = 0; i < 4; ++i) {
        const int ag = m0 + wv * 32 + i * 8 + lrow;
        aoff[i] = (size_t)ag * K + lcol8;
        const int bg = n0 + wv * 32 + i * 8 + lrow;
        boff[i] = (size_t)bg * K + lcol8;
    }
    f32x4 acc[4][4] = {};
    const int nk = K / 64;
    for (int kt = 0; kt < nk; ++kt) {
        __syncthreads();
        #pragma unroll
        for (int i = 0; i < 4; ++i)
            gload_lds16(A + aoff[i] + kt * 64, As + wv * 2048 + i * 512);
        #pragma unroll
        for (int i = 0; i < 4; ++i)
            gload_lds16(BT + boff[i] + kt * 64, Bs + wv * 2048 + i * 512);
        __syncthreads();
        #pragma unroll
        for (int ks = 0; ks < 2; ++ks) {
            bf16x8 af[4], bfv[4];
            #pragma unroll
            for (int i = 0; i < 4; ++i) {
                const int row = wr + i * 16 + fr;
                af[i] = ld8(As + row * 64 + (((ks * 4 + fg) ^ (row & 7)) * 8));
            }
            #pragma unroll
            for (int i = 0; i < 4; ++i) {
                const int row = wc + i * 16 + fr;
                bfv[i] = ld8(Bs + row * 64 + (((ks * 4 + fg) ^ (row & 7)) * 8));
            }
            #pragma unroll
            for (int mi = 0; mi < 4; ++mi)
                #pragma unroll
                for (int ni = 0; ni < 4; ++ni)
                    acc[mi][ni] = mfma16(af[mi], bfv[ni], acc[mi][ni]);
        }
    }
    #pragma unroll
    for (int mi = 0; mi < 4; ++mi) {
        #pragma unroll
        for (int ni = 0; ni < 4; ++ni) {
            const int col = n0 + wc + ni * 16 + fr;
            const float bv = bias[col];
            #pragma unroll
            for (int r = 0; r < 4; ++r) {
                const int row = m0 + wr + mi * 16 + fg * 4 + r;
                Cf[(size_t)row * 1024 + col] = acc[mi][ni][r] + bv;
            }
        }
    }
}

// ---------------- fused attention (R13-proven): swapped softmax, b64 sc, 3-barrier pipeline ----------------
__global__ __launch_bounds__(256, 2)
void attn_fused10(const u16* __restrict__ Qb, const u16* __restrict__ KVb,
                  const u16* __restrict__ Vtb, const u16* __restrict__ peb,
                  u16* __restrict__ O01, float* __restrict__ lsep,
                  u16* __restrict__ O2) {
    const int bid = blockIdx.x;
    const int xcd = bid & 7, ii = bid >> 3;
    const int G = xcd * 12 + (ii >> 4), qt = ii & 15;
    const int b = G / 24, rem = G - b * 24;
    const int h = rem / 3, sp = rem - (rem / 3) * 3;

    const int tid = threadIdx.x, w = tid >> 6, lane = tid & 63;
    const int fr = lane & 15, fg = lane >> 4;
    const int q0 = qt * 64, q0w = q0 + w * 16;
    const int n64 = min(2304, q0 + 1344) >> 6;
    const int base = n64 / 3, rm = n64 - base * 3;
    const int cbeg = sp * base + min(sp, rm);
    const int cnt = base + (sp < rm ? 1 : 0);
    const int kbeg = cbeg << 6, kend = (cbeg + cnt) << 6;

    __shared__ __align__(16) u16 Ks[64 * 128];
    __shared__ __align__(16) u16 Vs[128 * 64];
    __shared__ __align__(16) u16 PEs[2][64 * 128];
    __shared__ __align__(16) u16 sc[4][16][108];

    const u16* kvbase = KVb + (size_t)b * 2304 * 2048 + h * 128;
    const u16* vtbase = Vtb + (size_t)(b * 8 + h) * 128 * 2304;
    const u16* pebase = peb + (size_t)h * 2304 * 128;
    const float scale2 = 0.088388347648318447f * 1.4426950408889634f;

    bf16x8 qf[4];
    {
        const u16* qp = Qb + (size_t)(b * 1024 + q0w + fr) * 1024 + h * 128 + fg * 8;
        #pragma unroll
        for (int dc = 0; dc < 4; ++dc) qf[dc] = ld8(qp + dc * 32);
    }

    const u16* srcK[4];
    const u16* srcV[4];
    const u16* srcP[4];
    #pragma unroll
    for (int i = 0; i < 4; ++i) {
        const int kr = w * 16 + i * 4 + (lane >> 4);
        srcK[i] = kvbase + (size_t)kr * 2048 + (((lane & 15) ^ (kr & 7)) * 8);
        srcP[i] = pebase + (size_t)kr * 128  + (((lane & 15) ^ (kr & 7)) * 8);
        const int vr = w * 32 + i * 8 + (lane >> 3);
        srcV[i] = vtbase + (size_t)vr * 2304 + (((lane & 7) ^ (vr & 7)) * 8);
    }

    // prologue: stage K, V, PE-lo, PE-hi for chunk kbeg
    {
        const int cc0 = (kbeg - q0) >> 6;
        u16* lo = &PEs[(cc0 + 15) & 1][0];
        u16* up = &PEs[(cc0 + 16) & 1][0];
        const size_t jlo = (size_t)(kbeg - q0 + 960) * 128;
        const size_t jup = (size_t)(kbeg - q0 + 1024) * 128;
        #pragma unroll
        for (int i = 0; i < 4; ++i)
            gload_lds16(srcK[i] + (size_t)kbeg * 2048, Ks + w * 2048 + i * 512);
        #pragma unroll
        for (int i = 0; i < 4; ++i)
            gload_lds16(srcV[i] + kbeg, &Vs[0] + w * 2048 + i * 512);
        #pragma unroll
        for (int i = 0; i < 4; ++i)
            gload_lds16(srcP[i] + jlo, lo + w * 2048 + i * 512);
        #pragma unroll
        for (int i = 0; i < 4; ++i)
            gload_lds16(srcP[i] + jup, up + w * 2048 + i * 512);
    }

    f32x4 o[8] = {};
    float mrow = -1e30f, lrow = 0.0f;   // per-lane, q = q0w + fr

    for (int k0 = kbeg; k0 < kend; k0 += 64) {
        const int cc = (k0 - q0) >> 6;
        const bool more = (k0 + 64 < kend);
        __syncthreads();   // B1: drain staged loads

        // ---- S^T = K Q^T + PE^T band, LDS-fed, swapped args ----
        __builtin_amdgcn_s_setprio(1);
        f32x4 s[4] = {};
        #pragma unroll
        for (int kb = 0; kb < 4; ++kb) {
            const int row = kb * 16 + fr;
            #pragma unroll
            for (int dc = 0; dc < 4; ++dc) {
                bf16x8 kf = ld8(Ks + row * 128 + ((dc * 32 + fg * 8) ^ ((row & 7) << 3)));
                s[kb] = mfma16(kf, qf[dc], s[kb]);
            }
        }
        const u16* pl = &PEs[(cc + 15) & 1][0];
        const u16* pu = &PEs[(cc + 16) & 1][0];
        f32x4 pp[5] = {};
        #pragma unroll
        for (int jb = 0; jb < 5; ++jb) {
            const int lstart = 48 - 16 * w + 16 * jb;
            const u16* pbase = (lstart < 64) ? (pl + lstart * 128) : (pu + (lstart - 64) * 128);
            #pragma unroll
            for (int dc = 0; dc < 4; ++dc) {
                bf16x8 pf = ld8(pbase + fr * 128 + ((dc * 32 + fg * 8) ^ ((fr & 7) << 3)));
                pp[jb] = mfma16(pf, qf[dc], pp[jb]);
            }
        }
        __builtin_amdgcn_s_setprio(0);
        #pragma unroll
        for (int jb = 0; jb < 5; ++jb) {
            uint2 pk;
            pk.x = pk2bf(pp[jb][0], pp[jb][1]);
            pk.y = pk2bf(pp[jb][2], pp[jb][3]);
            *(uint2*)(&sc[w][fr][jb * 16 + fg * 4]) = pk;
        }
        asm volatile("s_waitcnt lgkmcnt(0)" ::: "memory");

        __syncthreads();   // B2: Ks/PEs reads complete -> safe to restage

        if (more) {
            #pragma unroll
            for (int i = 0; i < 4; ++i)
                gload_lds16(srcK[i] + (size_t)(k0 + 64) * 2048, Ks + w * 2048 + i * 512);
            u16* pslot = &PEs[(cc + 15) & 1][0];
            const size_t jnext = (size_t)(k0 - q0 + 1088) * 128;
            #pragma unroll
            for (int i = 0; i < 4; ++i)
                gload_lds16(srcP[i] + jnext, pslot + w * 2048 + i * 512);
        }

        // ---- combine + mask + online softmax: q = fr, k = k0 + kb*16 + fg*4 + r ----
        const bool need_mask = (k0 + 63) > (q0w + 1280);
        float pv[4][4];
        float mx = mrow;
        #pragma unroll
        for (int kb = 0; kb < 4; ++kb) {
            #pragma unroll
            for (int r = 0; r < 4; ++r) {
                float v = (s[kb][r] + bf2f(sc[w][fr][kb * 16 + fg * 4 + r + 15 - fr])) * scale2;
                if (need_mask && (k0 + kb * 16 + fg * 4 + r) > (q0w + fr + 1280)) v = -1e30f;
                pv[kb][r] = v;
                mx = fmaxf(mx, v);
            }
        }
        mx = fmaxf(mx, __shfl_xor(mx, 16));
        mx = fmaxf(mx, __shfl_xor(mx, 32));
        if (!__all(mx - mrow <= 8.0f)) {
            const float alpha = fexp2(mrow - mx);
            mrow = mx;
            lrow *= alpha;
            float a4[4];
            #pragma unroll
            for (int r = 0; r < 4; ++r) a4[r] = __shfl(alpha, fg * 4 + r);
            #pragma unroll
            for (int db = 0; db < 8; ++db)
                #pragma unroll
                for (int r = 0; r < 4; ++r) o[db][r] *= a4[r];
        }
        float rsum = 0.0f;
        #pragma unroll
        for (int kb = 0; kb < 4; ++kb)
            #pragma unroll
            for (int r = 0; r < 4; ++r) {
                const float p = fexp2(pv[kb][r] - mrow);
                pv[kb][r] = p;
                rsum += p;
            }
        rsum += __shfl_xor(rsum, 16);
        rsum += __shfl_xor(rsum, 32);
        lrow += rsum;
        #pragma unroll
        for (int kb = 0; kb < 4; ++kb) {
            uint2 pk;
            pk.x = pk2bf(pv[kb][0], pv[kb][1]);
            pk.y = pk2bf(pv[kb][2], pv[kb][3]);
            *(uint2*)(&sc[w][fr][kb * 16 + fg * 4]) = pk;
        }
        asm volatile("s_waitcnt lgkmcnt(0)" ::: "memory");
        // ---- O += P V ----
        __builtin_amdgcn_s_setprio(1);
        #pragma unroll
        for (int ks = 0; ks < 2; ++ks) {
            bf16x8 pa = __builtin_bit_cast(bf16x8, *(const uint4*)(&sc[w][fr][ks * 32 + fg * 8]));
            #pragma unroll
            for (int db = 0; db < 8; ++db) {
                const int d = db * 16 + fr;
                bf16x8 vf = ld8(Vs + d * 64 + ((ks * 32 + fg * 8) ^ ((d & 7) << 3)));
                o[db] = mfma16(pa, vf, o[db]);
            }
        }
        __builtin_amdgcn_s_setprio(0);

        __syncthreads();   // B3: Vs reads complete

        if (more) {
            #pragma unroll
            for (int i = 0; i < 4; ++i)
                gload_lds16(srcV[i] + (k0 + 64), &Vs[0] + w * 2048 + i * 512);
        }
    }
    // ---- epilogue: normalized partial + lse (log2 domain) ----
    const float inv = 1.0f / lrow;
    float inv4[4];
    #pragma unroll
    for (int r = 0; r < 4; ++r) inv4[r] = __shfl(inv, fg * 4 + r);
    u16* dst = (sp == 2) ? O2 : (O01 + (size_t)sp * 4194304);
    #pragma unroll
    for (int db = 0; db < 8; ++db)
        #pragma unroll
        for (int r = 0; r < 4; ++r)
            dst[(size_t)(b * 1024 + q0w + fg * 4 + r) * 1024 + h * 128 + db * 16 + fr]
                = f2bf(o[db][r] * inv4[r]);
    if (lane < 16)
        lsep[sp * 32768 + (b * 8 + h) * 1024 + q0w + lane] = mrow + flog2(lrow);
}

// combine 3 flash partials (lse in log2 domain)
__global__ void attn_combine(const u16* __restrict__ O01, const float* __restrict__ lsep,
                             u16* __restrict__ O2) {
    const int i = (blockIdx.x * 256 + threadIdx.x) * 8;
    const int row = i >> 10;
    const int b = row >> 10, q = row & 1023;
    const int h = (i & 1023) >> 7;
    const int li = (b * 8 + h) * 1024 + q;
    const float l0 = lsep[li], l1 = lsep[li + 32768], l2 = lsep[li + 65536];
    const float M = fmaxf(l0, fmaxf(l1, l2));
    const float w0 = fexp2(l0 - M), w1 = fexp2(l1 - M), w2 = fexp2(l2 - M);
    const float inv = 1.0f / (w0 + w1 + w2);
    uint4 a = *(const uint4*)(O01 + i);
    uint4 c = *(const uint4*)(O01 + 4194304 + i);
    uint4 e = *(const uint4*)(O2 + i);
    const u16* ap = (const u16*)&a;
    const u16* cp = (const u16*)&c;
    const u16* ep = (const u16*)&e;
    u16 ov[8];
    #pragma unroll
    for (int j = 0; j < 8; ++j)
        ov[j] = f2bf((w0 * bf2f(ap[j]) + w1 * bf2f(cp[j]) + w2 * bf2f(ep[j])) * inv);
    *(uint4*)(O2 + i) = *(const uint4*)ov;
}

// ---------------- launch ----------------

extern "C" void kernel_launch(void* const* d_in, const int* in_sizes, int n_in,
                              void* d_out, int out_size, void* d_ws, size_t ws_size,
                              hipStream_t stream) {
    const float* x     = (const float*)d_in[0];
    const float* mem   = (const float*)d_in[1];
    const float* cmem  = (const float*)d_in[2];
    const float* pos   = (const float*)d_in[3];
    const float* Wq    = (const float*)d_in[5];
    const float* Wkv   = (const float*)d_in[6];
    const float* Wout  = (const float*)d_in[7];
    const float* bout  = (const float*)d_in[8];
    const float* convw = (const float*)d_in[9];
    const float* convb = (const float*)d_in[10];
    float* out = (float*)d_out;

    u16* ws = (u16*)d_ws;
    size_t off = 0;
    u16* kvin   = ws + off; off += (size_t)9216 * 1024;   // also reused as O-partials
    u16* WqT    = ws + off; off += (size_t)1024 * 1024;
    u16* WkvT   = ws + off; off += (size_t)2048 * 1024;
    u16* WoutT  = ws + off; off += (size_t)1024 * 1024;
    u16* convWT = ws + off; off += (size_t)1024 * 4096;
    u16* peb    = ws + off; off += (size_t)8 * 2304 * 128;
    u16* Qb     = ws + off; off += (size_t)4096 * 1024;
    u16* KVb    = ws + off; off += (size_t)9216 * 2048;
    u16* Vtb    = ws + off; off += (size_t)4 * 8 * 128 * 2304;
    u16* attn   = ws + off; off += (size_t)4096 * 1024;

    u16* O01 = kvin;                             // splits 0,1: 2 x 4194304 u16
    float* lsep = (float*)(kvin + 8388608);      // 3 x 32768 f32
    u16* convPart = attn;                        // 4 x 1048576 u16 (dead until attn kernel)

    prep_all<<<16640, 256, 0, stream>>>(x, mem, cmem, pos, Wq, Wkv, Wout, convw,
                                        kvin, peb, WqT, WkvT, WoutT, convWT,
                                        out + 4194304);

    // merged conv-splitK + KV(+Vt) + Q GEMMs
    gemm_fused<<<1664, 256, 0, stream>>>(kvin, WqT, WkvT, convWT,
                                         Qb, KVb, Vtb, convPart);
    // new_cmem = sum conv partials + bias (before attn overwrites the partial buffer)
    conv_combine<<<1024, 256, 0, stream>>>(convPart, convb, out + 8388608);

    attn_fused10<<<dim3(1536), 256, 0, stream>>>(Qb, KVb, Vtb, peb, O01, lsep, attn);
    attn_combine<<<2048, 256, 0, stream>>>(O01, lsep, attn);

    // logits = attn_out @ Wout + b_out
    gemm_bt<<<256, 256, 0, stream>>>(attn, WoutT, out, bout, 1024);
    // aux_loss = 0
    hipMemsetAsync(out + 9437184, 0, 4, stream);
}